// Round 3
// baseline (63.492 us; speedup 1.0000x reference)
//
#include <hip/hip_runtime.h>
#include <stdint.h>

#define NB   16
#define CIN  32
#define COUT 32
#define HH   256
#define WW   256
#define HWSZ (HH * WW)
#define EPSV 1e-5f
#define RR   4               // output rows per block
#define SR   (RR + 2)        // staged rows (with halo)
#define TSTRIDE 260          // row stride: 256 data + 4 pad, keeps rows 16B-aligned

// ---------------------------------------------------------------------------
// Kernel 1: pack weights + per-boundary-class correction table.
// pw[o*9+t]: bit c = (w[o,c,kh,kw] < 0)   (wb = sign(sign(w)+0.01): -1 iff w<0)
// offf[cls*32+o] = nv*32 + 2*sum_{invalid taps} popc(pw), cls = rowclass*3+colclass,
// so that  result = offf - 2*acc_full  with zero-padded tiles.
// ---------------------------------------------------------------------------
__global__ __launch_bounds__(288) void pack_w_kernel(const float* __restrict__ wt,
                                                     uint32_t* __restrict__ pw,
                                                     float* __restrict__ offf) {
    __shared__ uint32_t pws[COUT * 9];
    const int j = threadIdx.x;            // 0..287
    if (j < COUT * 9) {
        const int o = j / 9, t = j % 9;
        uint32_t bits = 0;
#pragma unroll
        for (int c = 0; c < CIN; ++c) {
            const float v = wt[(o * CIN + c) * 9 + t];
            bits |= (v < 0.f) ? (1u << c) : 0u;
        }
        pw[j] = bits;
        pws[j] = bits;
    }
    __syncthreads();
    {
        const int cls = j / COUT;         // 0..8
        const int o   = j % COUT;
        const int rc = cls / 3, cc = cls % 3;
        int inv = 0, nv = 0;
#pragma unroll
        for (int dh = 0; dh < 3; ++dh)
#pragma unroll
            for (int dw = 0; dw < 3; ++dw) {
                const bool bad = (rc == 0 && dh == 0) || (rc == 2 && dh == 2) ||
                                 (cc == 0 && dw == 0) || (cc == 2 && dw == 2);
                if (bad) inv += __popc(pws[o * 9 + dh * 3 + dw]);
                else     nv++;
            }
        offf[j] = (float)(nv * 32 + 2 * inv);
    }
}

// ---------------------------------------------------------------------------
// Kernel 2 (fused, multi-row): pack 6 input rows -> LDS, then XNOR-popcount
// conv for 4 output rows + BN + ReLU. XCD-chunked block swizzle for L2 reuse
// of the shared halo rows; non-temporal output stores.
// ---------------------------------------------------------------------------
__global__ __launch_bounds__(256) void biconv_fused(
    const uint32_t* __restrict__ x, const uint32_t* __restrict__ pw,
    const float* __restrict__ offf,
    const float* __restrict__ gamma, const float* __restrict__ beta,
    const float* __restrict__ rmean, const float* __restrict__ rvar,
    float* __restrict__ out) {
    const uint32_t bid = blockIdx.x;                        // 0..1023
    const uint32_t wg  = ((bid & 7u) << 7) | (bid >> 3);    // bijective XCD chunking
    const int n   = wg >> 6;                                // 0..15
    const int hb  = wg & 63;                                // 0..63
    const int h0  = hb << 2;
    const int tid = threadIdx.x;

    __shared__ uint4    wsh4[COUT * 3];     // 12 words per o (9 used)
    __shared__ float    offsh[9 * COUT];
    __shared__ float    sc[COUT], bi[COUT];
    __shared__ uint32_t tile[SR][TSTRIDE];  // data [0..255], zero pads [256..259]

    // ---- stage weights (padded), off-table, BN consts, row pads ----
    uint32_t* wshw = reinterpret_cast<uint32_t*>(wsh4);
#pragma unroll
    for (int i = tid; i < COUT * 12; i += 256) {
        const int o = i / 12, t = i % 12;
        wshw[i] = (t < 9) ? pw[o * 9 + t] : 0u;
    }
#pragma unroll
    for (int i = tid; i < 9 * COUT; i += 256) offsh[i] = offf[i];
    if (tid < COUT) {
        const float inv = gamma[tid] * rsqrtf(rvar[tid] + EPSV);
        sc[tid] = inv;
        bi[tid] = beta[tid] - rmean[tid] * inv;
    }
    if (tid < SR) {
        tile[tid][WW + 0] = 0u; tile[tid][WW + 1] = 0u;
        tile[tid][WW + 2] = 0u; tile[tid][WW + 3] = 0u;
    }

    // ---- pack SR rows: task q -> staged row q>>6, quad q&63 (4 words) ----
    const uint32_t* xn = x + (size_t)n * (CIN * HWSZ);
#pragma unroll
    for (int it = 0; it < 2; ++it) {
        const int q = tid + it * 256;
        if (q < SR * 64) {
            const int r  = q >> 6;
            const int qq = q & 63;
            const int hr = h0 - 1 + r;
            uint32_t b0 = 0, b1 = 0, b2 = 0, b3 = 0;
            if (hr >= 0 && hr < HH) {
                const uint32_t* xp = xn + hr * WW + (qq << 2);
#pragma unroll
                for (int c = 0; c < CIN; ++c) {
                    const uint4 v = *reinterpret_cast<const uint4*>(xp + (size_t)c * HWSZ);
                    b0 |= (v.x >> 31) << c;
                    b1 |= (v.y >> 31) << c;
                    b2 |= (v.z >> 31) << c;
                    b3 |= (v.w >> 31) << c;
                }
            }
            *reinterpret_cast<uint4*>(&tile[r][qq << 2]) = make_uint4(b0, b1, b2, b3);
        }
    }
    __syncthreads();

    // ---- conv: thread = one w column, RR rows ----
    const int w  = tid;
    const int wl = (w == 0) ? WW : (w - 1);          // left tap (WW = zero pad slot)
    uint32_t p[SR][3];
#pragma unroll
    for (int j = 0; j < SR; ++j) {
        p[j][0] = tile[j][wl];
        p[j][1] = tile[j][w];
        p[j][2] = tile[j][w + 1];                    // w=255 -> pad slot 256 = 0
    }
    const int ccls = (w == 0) ? 0 : ((w == WW - 1) ? 2 : 1);
    int offidx[RR];
#pragma unroll
    for (int r = 0; r < RR; ++r) {
        const int h  = h0 + r;
        const int rc = (h == 0) ? 0 : ((h == HH - 1) ? 2 : 1);
        offidx[r] = (rc * 3 + ccls) * COUT;
    }
    float* outp = out + (size_t)n * (COUT * HWSZ) + (size_t)h0 * WW + w;
#pragma unroll 4
    for (int o = 0; o < COUT; ++o) {
        const uint4 wa = wsh4[o * 3 + 0];
        const uint4 wb = wsh4[o * 3 + 1];
        const uint4 wc = wsh4[o * 3 + 2];
        const float scv = sc[o], biv = bi[o];
#pragma unroll
        for (int r = 0; r < RR; ++r) {
            int acc;
            acc  = __popc(p[r + 0][0] ^ wa.x);
            acc += __popc(p[r + 0][1] ^ wa.y);
            acc += __popc(p[r + 0][2] ^ wa.z);
            acc += __popc(p[r + 1][0] ^ wa.w);
            acc += __popc(p[r + 1][1] ^ wb.x);
            acc += __popc(p[r + 1][2] ^ wb.y);
            acc += __popc(p[r + 2][0] ^ wb.z);
            acc += __popc(p[r + 2][1] ^ wb.w);
            acc += __popc(p[r + 2][2] ^ wc.x);
            const float s = fmaf(-2.0f, (float)acc, offsh[offidx[r] + o]);
            const float v = fmaf(s, scv, biv);
            __builtin_nontemporal_store(v > 0.f ? v : 0.f,
                                        outp + (size_t)o * HWSZ + r * WW);
        }
    }
}

// ---------------------------------------------------------------------------
extern "C" void kernel_launch(void* const* d_in, const int* in_sizes, int n_in,
                              void* d_out, int out_size, void* d_ws, size_t ws_size,
                              hipStream_t stream) {
    const float* x     = (const float*)d_in[0];
    const float* wt    = (const float*)d_in[1];
    const float* gamma = (const float*)d_in[2];
    const float* beta  = (const float*)d_in[3];
    const float* rmean = (const float*)d_in[4];
    const float* rvar  = (const float*)d_in[5];
    float* out = (float*)d_out;

    uint32_t* pw   = (uint32_t*)d_ws;          // 288 words
    float*    offf = (float*)(pw + 288);       // 288 floats

    pack_w_kernel<<<dim3(1), dim3(288), 0, stream>>>(wt, pw, offf);
    biconv_fused<<<dim3(NB * HH / RR), dim3(256), 0, stream>>>(
        (const uint32_t*)x, pw, offf, gamma, beta, rmean, rvar, out);
}

// Round 4
// 54.692 us; speedup vs baseline: 1.1609x; 1.1609x over previous
//
#include <hip/hip_runtime.h>
#include <stdint.h>

#define NB   16
#define CIN  32
#define COUT 32
#define HH   256
#define WW   256
#define HWSZ (HH * WW)
#define EPSV 1e-5f

typedef int v4i  __attribute__((ext_vector_type(4)));
typedef int v16i __attribute__((ext_vector_type(16)));

// ---------------------------------------------------------------------------
// Kernel 1 (tiny, 1 block): weight pack -> MFMA A-fragments (+BN/correction
// tables). wb = sign(sign(w)+0.01): -1 iff w<0, +1 otherwise.
//   afrag[t][lane] = 16 i8 (+-1): o = lane&31, ch = (lane>>5)*16 + e
//   c1f[o]        = 2 * gamma/sqrt(var+eps)
//   c0f[cls][o]   = beta - mean*inv - Wsum[cls][o]*inv
// where Wsum = sum of wb over VALID taps of boundary class cls, so that with
// B in {0,1} (1 iff x>=0, pads=0):  result = acc*c1 + c0.
// ---------------------------------------------------------------------------
__global__ __launch_bounds__(288) void pack_w_kernel(
    const float* __restrict__ wt, const float* __restrict__ gamma,
    const float* __restrict__ beta, const float* __restrict__ rmean,
    const float* __restrict__ rvar, uint4* __restrict__ afrag,
    float* __restrict__ c0f, float* __restrict__ c1f) {
    __shared__ uint32_t pws[COUT * 9];
    const int j = threadIdx.x;                 // 0..287
    if (j < COUT * 9) {
        const int o = j / 9, t = j % 9;
        uint32_t bits = 0;
#pragma unroll
        for (int c = 0; c < CIN; ++c)
            bits |= (wt[(o * CIN + c) * 9 + t] < 0.f) ? (1u << c) : 0u;  // 1 = -1
        pws[j] = bits;
    }
    __syncthreads();
    // ---- A fragments (threads 0..63 = lanes) ----
    if (j < 64) {
        const int sh = (j & 32) >> 1;          // ch offset 0/16
#pragma unroll
        for (int t = 0; t < 9; ++t) {
            const uint32_t chunk = pws[(j & 31) * 9 + t] >> sh;
            uint32_t w[4];
#pragma unroll
            for (int k = 0; k < 4; ++k) {
                const uint32_t y = (((chunk >> (4 * k)) & 0xFu) * 0x204081u) & 0x01010101u;
                w[k] = (y * 0xFEu) | 0x01010101u;   // bit? 0xFF(-1) : 0x01(+1)
            }
            afrag[t * 64 + j] = make_uint4(w[0], w[1], w[2], w[3]);
        }
    }
    // ---- BN + correction tables ----
    {
        const int cls = j >> 5;                // 0..8
        const int o   = j & 31;
        const int rc = cls / 3, cc = cls % 3;
        int wsum = 0;
#pragma unroll
        for (int dh = 0; dh < 3; ++dh)
#pragma unroll
            for (int dw = 0; dw < 3; ++dw) {
                const bool bad = (rc == 0 && dh == 0) || (rc == 2 && dh == 2) ||
                                 (cc == 0 && dw == 0) || (cc == 2 && dw == 2);
                if (!bad) wsum += 32 - 2 * __popc(pws[o * 9 + dh * 3 + dw]);
            }
        const float inv = gamma[o] * rsqrtf(rvar[o] + EPSV);
        c0f[cls * 32 + o] = beta[o] - rmean[o] * inv - (float)wsum * inv;
        if (cls == 0) c1f[o] = 2.0f * inv;
    }
}

// ---------------------------------------------------------------------------
// Kernel 2: fused binarize + implicit-GEMM i8-MFMA conv + BN + ReLU.
// Block = (n, 2 output rows). 256 threads / 4 waves. Bit-packed 4-row LDS
// tile (bit c = x>=0); per 32-pixel tile each lane expands its 16-channel
// half of 9 tap-words into {0,1} i8 B-fragments and runs 9 MFMAs.
// ---------------------------------------------------------------------------
__global__ __launch_bounds__(256) void biconv_mfma(
    const uint32_t* __restrict__ x, const uint4* __restrict__ afrag,
    const float* __restrict__ c0f, const float* __restrict__ c1f,
    float* __restrict__ out) {
    const uint32_t bid = blockIdx.x;                       // 0..2047
    const uint32_t wg  = ((bid & 7u) << 8) | (bid >> 3);   // bijective XCD chunk
    const int n   = wg >> 7;                               // 0..15
    const int h0  = (wg & 127) << 1;                       // 0,2,..,254
    const int tid  = threadIdx.x;
    const int lane = tid & 63;
    const int wave = tid >> 6;

    __shared__ uint32_t tiles[4 * 264];   // 4 rows; data at wi=4..259, pads 3 & 260
    __shared__ float    c0sh[9 * COUT];
    __shared__ float    c1sh[COUT];

    for (int i = tid; i < 9 * COUT; i += 256) c0sh[i] = c0f[i];
    if (tid < COUT) c1sh[tid] = c1f[tid];
    if (tid < 8) tiles[(tid >> 1) * 264 + ((tid & 1) ? 260 : 3)] = 0u;

    // ---- pack 4 rows (1 task/thread): r = wave, quad q ----
    {
        const int r = wave, q = tid & 63;
        const int hr = h0 - 1 + r;
        uint32_t b0 = 0, b1 = 0, b2 = 0, b3 = 0;
        if (hr >= 0 && hr < HH) {
            const uint32_t* xp = x + (size_t)n * (CIN * HWSZ) + hr * WW + (q << 2);
#pragma unroll
            for (int c = 0; c < CIN; ++c) {
                const uint4 v = *reinterpret_cast<const uint4*>(xp + (size_t)c * HWSZ);
                b0 |= (v.x >> 31) << c;
                b1 |= (v.y >> 31) << c;
                b2 |= (v.z >> 31) << c;
                b3 |= (v.w >> 31) << c;
            }
            b0 = ~b0; b1 = ~b1; b2 = ~b2; b3 = ~b3;   // bit = (x >= 0)
        }
        *reinterpret_cast<uint4*>(&tiles[r * 264 + (q << 2) + 4]) =
            make_uint4(b0, b1, b2, b3);
    }
    __syncthreads();

    // ---- A fragments ----
    v4i af[9];
#pragma unroll
    for (int t = 0; t < 9; ++t)
        af[t] = *reinterpret_cast<const v4i*>(&afrag[t * 64 + lane]);
    const int shv = (lane & 32) >> 1;          // 0 / 16 : channel half
    const int og  = (lane >> 5) << 2;          // C/D row offset 0 / 4

#pragma unroll
    for (int r = 0; r < 2; ++r) {
        const int h  = h0 + r;
        const int rc = (h == 0) ? 0 : ((h == HH - 1) ? 2 : 1);
#pragma unroll
        for (int tw = 0; tw < 2; ++tw) {
            const int w0    = (wave << 6) + (tw << 5);
            const int pixel = w0 + (lane & 31);
            const uint32_t* bp = &tiles[r * 264 + pixel + 3];  // +dh*264+dw
            v16i acc = {0};
#pragma unroll
            for (int dh = 0; dh < 3; ++dh) {
#pragma unroll
                for (int dw = 0; dw < 3; ++dw) {
                    const uint32_t h16 = bp[dh * 264 + dw] >> shv;
                    v4i b;
                    b.x = (int)(((( h16        ) & 0xFu) * 0x204081u) & 0x01010101u);
                    b.y = (int)((((h16 >> 4   ) & 0xFu) * 0x204081u) & 0x01010101u);
                    b.z = (int)((((h16 >> 8   ) & 0xFu) * 0x204081u) & 0x01010101u);
                    b.w = (int)((((h16 >> 12  ) & 0xFu) * 0x204081u) & 0x01010101u);
                    acc = __builtin_amdgcn_mfma_i32_32x32x32_i8(af[dh * 3 + dw], b,
                                                                acc, 0, 0, 0);
                }
            }
            // ---- epilogue: C/D row = (e&3)+8*(e>>2)+og, col = pixel ----
            const int ccls = (pixel == 0) ? 0 : ((pixel == WW - 1) ? 2 : 1);
            const float* c0b = &c0sh[(rc * 3 + ccls) * 32];
            float* outp = out + (size_t)n * (COUT * HWSZ) + (size_t)h * WW + pixel;
#pragma unroll
            for (int e = 0; e < 16; ++e) {
                const int o = (e & 3) + ((e >> 2) << 3) + og;
                const float v = fmaf((float)acc[e], c1sh[o], c0b[o]);
                __builtin_nontemporal_store(v > 0.f ? v : 0.f,
                                            outp + (size_t)o * HWSZ);
            }
        }
    }
}

// ---------------------------------------------------------------------------
extern "C" void kernel_launch(void* const* d_in, const int* in_sizes, int n_in,
                              void* d_out, int out_size, void* d_ws, size_t ws_size,
                              hipStream_t stream) {
    const float* x     = (const float*)d_in[0];
    const float* wt    = (const float*)d_in[1];
    const float* gamma = (const float*)d_in[2];
    const float* beta  = (const float*)d_in[3];
    const float* rmean = (const float*)d_in[4];
    const float* rvar  = (const float*)d_in[5];
    float* out = (float*)d_out;

    uint4* afrag = (uint4*)d_ws;                           // 9*64*16 = 9216 B
    float* c0f   = (float*)((char*)d_ws + 9216);           // 288 floats
    float* c1f   = c0f + 288;                              // 32 floats

    pack_w_kernel<<<dim3(1), dim3(288), 0, stream>>>(wt, gamma, beta, rmean,
                                                     rvar, afrag, c0f, c1f);
    biconv_mfma<<<dim3(NB * HH / 2), dim3(256), 0, stream>>>(
        (const uint32_t*)x, afrag, c0f, c1f, out);
}